// Round 3
// baseline (1110.827 us; speedup 1.0000x reference)
//
#include <hip/hip_runtime.h>
#include <hip/hip_bf16.h>

// Graph message-passing layer, bf16 MFMA implementation, v3.
// Edge path: swapped GEMMs (weights = A from swizzled LDS, gathered features = B),
// GEMM1->GEMM2 h-transpose via per-wave swizzled LDS buffer (aliased over the
// W1 LDS region, which is dead after GEMM1).
// N=10000 nodes, E=640000 edges, F=M=O=128.

#define NN 10000
#define NE 640000

typedef __attribute__((ext_vector_type(8))) short short8;
typedef __attribute__((ext_vector_type(4))) short short4v;
typedef __attribute__((ext_vector_type(4))) float floatx4;

__device__ __forceinline__ short f2bf(float f) {
    union { float f; unsigned u; } v; v.f = f;
    unsigned r = v.u + 0x7fffu + ((v.u >> 16) & 1u);   // RNE, NaN-free inputs
    return (short)(r >> 16);
}

__device__ __forceinline__ float sigmoidf_(float x) {
    return __builtin_amdgcn_rcpf(1.f + __expf(-x));
}
__device__ __forceinline__ float softsignf_(float x) {
    return x * __builtin_amdgcn_rcpf(1.f + fabsf(x));
}

// ---------- prep kernels ----------

// features f32 -> bf16, 4 elems/thread
__global__ void feat2bf(const float* __restrict__ src, short* __restrict__ dst, int n4) {
    int i = blockIdx.x * 256 + threadIdx.x;
    if (i >= n4) return;
    float4 v = ((const float4*)src)[i];
    short4v o;
    o[0] = f2bf(v.x); o[1] = f2bf(v.y); o[2] = f2bf(v.z); o[3] = f2bf(v.w);
    ((short4v*)dst)[i] = o;
}

// dst[m][k ^ ((m&7)<<3)] = bf16(src[k][m]) : transposed + XOR-swizzled so the
// edge kernel's linear LDS copy yields conflict-free ds_read_b128 A-fragments.
__global__ void prep_w_swz(const float* __restrict__ src, short* __restrict__ dst,
                           int K, int C) {
    int i = blockIdx.x * 256 + threadIdx.x;
    if (i >= K * C) return;
    int m = i / K, k = i - m * K;
    dst[m * K + (k ^ ((m & 7) << 3))] = f2bf(src[k * C + m]);
}

// plain transpose (node kernel path): dst[c][k] = bf16(src[k][c])
__global__ void prep_transpose(const float* __restrict__ src,
                               short* __restrict__ dst, int K, int C) {
    int i = blockIdx.x * 256 + threadIdx.x;
    if (i >= K * C) return;
    int c = i / K, k = i - c * K;
    dst[i] = f2bf(src[k * C + c]);
}

// ---------- edge kernel ----------
// 512 threads = 8 waves; 32 edges/wave (2 groups of 16); 256 edges/block.
// GEMM1 (swapped): hT[128][16] = Wm1T(A, LDS) x msg_inT(B, gathered), K=256.
// h transpose via per-wave swizzled LDS buffer (aliased over W1 region).
// GEMM2 (swapped): msgT[128][16] = Wm2T(A, LDS) x hT(B, LDS), K=128.
__global__ __launch_bounds__(512, 2) void edge_kernel(
    const short* __restrict__ featbf,
    const int* __restrict__ rows,
    const int* __restrict__ cols,
    const short* __restrict__ W12,      // swizzled: W1 [128][256] | W2 [128][128]
    const float* __restrict__ bm1,
    const float* __restrict__ bm2,
    float* __restrict__ agg)
{
    __shared__ __align__(16) short wlds[49152];   // 96 KB: W1 | W2
    __shared__ float biasb[256];                  // bm1 | bm2
    const int tid = threadIdx.x;
    const int w = tid >> 6, l = tid & 63;
    const int q = l >> 4, l15 = l & 15;

    // stage weights (linear copy; source is pre-swizzled)
    {
        const short8* gs = (const short8*)W12;
        short8* ls = (short8*)wlds;
#pragma unroll
        for (int i = 0; i < 12; ++i) ls[i * 512 + tid] = gs[i * 512 + tid];
        if (tid < 128) biasb[tid] = bm1[tid];
        else if (tid < 256) biasb[tid] = bm2[tid - 128];
    }
    __syncthreads();

    const int ebase = blockIdx.x * 256 + w * 32;
    int nodeA[2];
    const short* sp[2];
    const short* dp[2];
#pragma unroll
    for (int eg = 0; eg < 2; ++eg) {
        int e = ebase + eg * 16 + l15;
        int ns = rows[e], nd = cols[e];
        nodeA[eg] = ns;
        sp[eg] = featbf + (size_t)ns * 128;
        dp[eg] = featbf + (size_t)nd * 128;
    }

    // ---- GEMM1 ----
    floatx4 acc1[8][2];
#pragma unroll
    for (int mt = 0; mt < 8; ++mt)
#pragma unroll
        for (int eg = 0; eg < 2; ++eg) acc1[mt][eg] = (floatx4)(0.f);

#pragma unroll
    for (int kk = 0; kk < 8; ++kk) {
        short8 bfr[2];
#pragma unroll
        for (int eg = 0; eg < 2; ++eg) {
            const short* p = (kk < 4) ? (sp[eg] + kk * 32 + q * 8)
                                      : (dp[eg] + (kk - 4) * 32 + q * 8);
            bfr[eg] = *(const short8*)p;
        }
#pragma unroll
        for (int mt = 0; mt < 8; ++mt) {
            const int m = mt * 16 + l15;
            const int idx = m * 256 + ((kk * 32 + q * 8) ^ ((m & 7) << 3));
            short8 afr = *(const short8*)(wlds + idx);
#pragma unroll
            for (int eg = 0; eg < 2; ++eg)
                acc1[mt][eg] = __builtin_amdgcn_mfma_f32_16x16x32_bf16(
                    afr, bfr[eg], acc1[mt][eg], 0, 0, 0);
        }
    }

    // W1 region of LDS (first 65536 B) is dead from here on; reuse it for the
    // per-wave h-transpose buffers. Barrier so no wave still reads W1.
    __syncthreads();
    short (*hb)[16][128] = (short (*)[16][128])wlds;   // [8 waves][16 e][128 k]
    const int swz = (l15 & 7) << 3;

#pragma unroll
    for (int eg = 0; eg < 2; ++eg) {
        // ---- bias + sigmoid + transpose to LDS ----
        // lane holds hT[m][e=l15], m = mt*16 + q*4 + r  ->  hb[w][l15][m ^ swz]
#pragma unroll
        for (int mt = 0; mt < 8; ++mt) {
            const int k0 = mt * 16 + q * 4;
            short4v hv;
            hv[0] = f2bf(sigmoidf_(acc1[mt][eg][0] + biasb[k0 + 0]));
            hv[1] = f2bf(sigmoidf_(acc1[mt][eg][1] + biasb[k0 + 1]));
            hv[2] = f2bf(sigmoidf_(acc1[mt][eg][2] + biasb[k0 + 2]));
            hv[3] = f2bf(sigmoidf_(acc1[mt][eg][3] + biasb[k0 + 3]));
            *(short4v*)&hb[w][l15][k0 ^ swz] = hv;
        }

        // ---- GEMM2 ----
        floatx4 acc2[8];
#pragma unroll
        for (int i = 0; i < 8; ++i) acc2[i] = (floatx4)(0.f);
#pragma unroll
        for (int kk2 = 0; kk2 < 4; ++kk2) {
            short8 bfrag = *(const short8*)&hb[w][l15][(kk2 * 32 + q * 8) ^ swz];
#pragma unroll
            for (int mt = 0; mt < 8; ++mt) {
                const int m = mt * 16 + l15;
                const int idx = 32768 + m * 128 + ((kk2 * 32 + q * 8) ^ ((m & 7) << 3));
                short8 afr = *(const short8*)(wlds + idx);
                acc2[mt] = __builtin_amdgcn_mfma_f32_16x16x32_bf16(
                    afr, bfrag, acc2[mt], 0, 0, 0);
            }
        }

        // ---- bias + softsign + atomic scatter ----
#pragma unroll
        for (int mt = 0; mt < 8; ++mt) {
            const int mbase = mt * 16 + q * 4;
            float* ap = agg + (size_t)nodeA[eg] * 128 + mbase;
            atomicAdd(ap + 0, softsignf_(acc2[mt][0] + biasb[128 + mbase + 0]));
            atomicAdd(ap + 1, softsignf_(acc2[mt][1] + biasb[128 + mbase + 1]));
            atomicAdd(ap + 2, softsignf_(acc2[mt][2] + biasb[128 + mbase + 2]));
            atomicAdd(ap + 3, softsignf_(acc2[mt][3] + biasb[128 + mbase + 3]));
        }
    }
}

// ---------- node kernel (unchanged, R1-verified) ----------
__global__ __launch_bounds__(256) void node_kernel(
    const float* __restrict__ feat,
    const float* __restrict__ agg,
    const float* __restrict__ temb,
    const short* __restrict__ Wf1T,
    const float* __restrict__ bf1v,
    const short* __restrict__ Wf2T,
    const float* __restrict__ bf2v,
    float* __restrict__ out)
{
    __shared__ __align__(16) short gbuf[4][16][128];
    const int tid = threadIdx.x;
    const int w = tid >> 6, l = tid & 63;
    const int l15 = l & 15, q = l >> 4;
    const int nbase = blockIdx.x * 64 + w * 16;
    if (nbase >= NN) return;

    const int nA = nbase + l15;
    const float* p0 = feat + (size_t)nA * 128 + q * 8;
    const float* p1 = agg + (size_t)nA * 128 + q * 8;
    const float* p2 = temb + (size_t)nA * 128 + q * 8;

    floatx4 acc[8];
#pragma unroll
    for (int i = 0; i < 8; ++i) acc[i] = (floatx4)(0.f);

#pragma unroll
    for (int kk = 0; kk < 12; ++kk) {                   // K = 384 = 12 x 32
        const float* ap = (kk < 4) ? (p0 + kk * 32)
                        : (kk < 8) ? (p1 + (kk - 4) * 32)
                                   : (p2 + (kk - 8) * 32);
        const float4 a0 = *(const float4*)(ap);
        const float4 a1 = *(const float4*)(ap + 4);
        short8 af;
        af[0] = f2bf(sigmoidf_(a0.x)); af[1] = f2bf(sigmoidf_(a0.y));
        af[2] = f2bf(sigmoidf_(a0.z)); af[3] = f2bf(sigmoidf_(a0.w));
        af[4] = f2bf(sigmoidf_(a1.x)); af[5] = f2bf(sigmoidf_(a1.y));
        af[6] = f2bf(sigmoidf_(a1.z)); af[7] = f2bf(sigmoidf_(a1.w));
        const int krow = kk * 32 + q * 8;
#pragma unroll
        for (int ct = 0; ct < 8; ++ct) {
            const int col = ct * 16 + l15;
            short8 bf = *(const short8*)(Wf1T + col * 384 + krow);
            acc[ct] = __builtin_amdgcn_mfma_f32_16x16x32_bf16(af, bf, acc[ct], 0, 0, 0);
        }
    }

#pragma unroll
    for (int ct = 0; ct < 8; ++ct) {
        const int col = ct * 16 + l15;
        const float b = bf1v[col];
#pragma unroll
        for (int r = 0; r < 4; ++r) {
            gbuf[w][q * 4 + r][col] = f2bf(sigmoidf_(acc[ct][r] + b));
        }
    }

    floatx4 acc2[8];
#pragma unroll
    for (int i = 0; i < 8; ++i) acc2[i] = (floatx4)(0.f);
#pragma unroll
    for (int kk = 0; kk < 4; ++kk) {
        const int krow = kk * 32 + q * 8;
        short8 af = *(const short8*)(&gbuf[w][l15][krow]);
#pragma unroll
        for (int ct = 0; ct < 8; ++ct) {
            const int col = ct * 16 + l15;
            short8 bf = *(const short8*)(Wf2T + col * 128 + krow);
            acc2[ct] = __builtin_amdgcn_mfma_f32_16x16x32_bf16(af, bf, acc2[ct], 0, 0, 0);
        }
    }

#pragma unroll
    for (int ct = 0; ct < 8; ++ct) {
        const int col = ct * 16 + l15;
        const float b = bf2v[col];
#pragma unroll
        for (int r = 0; r < 4; ++r) {
            const int node = nbase + q * 4 + r;
            out[(size_t)node * 128 + col] = softsignf_(acc2[ct][r] + b);
        }
    }
}

extern "C" void kernel_launch(void* const* d_in, const int* in_sizes, int n_in,
                              void* d_out, int out_size, void* d_ws, size_t ws_size,
                              hipStream_t stream)
{
    const float* feat = (const float*)d_in[0];
    const int* rows = (const int*)d_in[1];
    const int* cols = (const int*)d_in[2];
    const float* temb = (const float*)d_in[3];
    const float* Wm1 = (const float*)d_in[4];
    const float* bm1 = (const float*)d_in[5];
    const float* Wm2 = (const float*)d_in[6];
    const float* bm2 = (const float*)d_in[7];
    const float* Wf1 = (const float*)d_in[8];
    const float* bf1 = (const float*)d_in[9];
    const float* Wf2 = (const float*)d_in[10];
    const float* bf2 = (const float*)d_in[11];
    float* out = (float*)d_out;

    // Workspace layout (16B-aligned):
    //   agg    f32  [10000][128]      5,120,000 B
    //   featbf bf16 [10000][128]      2,560,000 B
    //   W12    bf16 swz W1|W2            98,304 B
    //   Wf1T   bf16 [128][384]           98,304 B
    //   Wf2T   bf16 [128][128]           32,768 B
    char* ws = (char*)d_ws;
    float* agg   = (float*)ws;
    short* fbf   = (short*)(ws + 5120000);
    short* W12   = (short*)(ws + 5120000 + 2560000);
    short* Wf1T  = (short*)(ws + 5120000 + 2560000 + 98304);
    short* Wf2T  = (short*)(ws + 5120000 + 2560000 + 98304 + 98304);

    hipMemsetAsync(agg, 0, (size_t)NN * 128 * sizeof(float), stream);
    feat2bf<<<(NN * 128 / 4 + 255) / 256, 256, 0, stream>>>(feat, fbf, NN * 128 / 4);
    prep_w_swz<<<(256 * 128 + 255) / 256, 256, 0, stream>>>(Wm1, W12, 256, 128);
    prep_w_swz<<<(128 * 128 + 255) / 256, 256, 0, stream>>>(Wm2, W12 + 32768, 128, 128);
    prep_transpose<<<(384 * 128 + 255) / 256, 256, 0, stream>>>(Wf1, Wf1T, 384, 128);
    prep_transpose<<<(128 * 128 + 255) / 256, 256, 0, stream>>>(Wf2, Wf2T, 128, 128);

    edge_kernel<<<NE / 256, 512, 0, stream>>>(fbf, rows, cols, W12, bm1, bm2, agg);
    node_kernel<<<(NN + 63) / 64, 256, 0, stream>>>(feat, agg, temb, Wf1T, bf1, Wf2T, bf2, out);
}

// Round 4
// 350.681 us; speedup vs baseline: 3.1676x; 3.1676x over previous
//
#include <hip/hip_runtime.h>
#include <hip/hip_bf16.h>

// Graph message-passing layer, bf16 MFMA implementation, v4.
// Edge path: swapped GEMMs (weights = A from swizzled LDS, gathered features = B).
// h (GEMM1->GEMM2) and msg (GEMM2->scatter) both round-trip through a per-wave
// 4 KB LDS buffer aliased over the dead W1 region. Scatter uses R1's pattern
// (4 nodes x 16 consecutive cols per instruction -> full-line atomic writes).
// 1024-thread blocks (16 waves) for occupancy.
// N=10000 nodes, E=640000 edges, F=M=O=128.

#define NN 10000
#define NE 640000

typedef __attribute__((ext_vector_type(8))) short short8;
typedef __attribute__((ext_vector_type(4))) short short4v;
typedef __attribute__((ext_vector_type(4))) float floatx4;

__device__ __forceinline__ short f2bf(float f) {
    union { float f; unsigned u; } v; v.f = f;
    unsigned r = v.u + 0x7fffu + ((v.u >> 16) & 1u);   // RNE, NaN-free inputs
    return (short)(r >> 16);
}
__device__ __forceinline__ float bf2f(short s) {
    union { unsigned u; float f; } v; v.u = ((unsigned)(unsigned short)s) << 16;
    return v.f;
}

__device__ __forceinline__ float sigmoidf_(float x) {
    return __builtin_amdgcn_rcpf(1.f + __expf(-x));
}
__device__ __forceinline__ float softsignf_(float x) {
    return x * __builtin_amdgcn_rcpf(1.f + fabsf(x));
}

// ---------- prep kernels ----------

// features f32 -> bf16, 4 elems/thread
__global__ void feat2bf(const float* __restrict__ src, short* __restrict__ dst, int n4) {
    int i = blockIdx.x * 256 + threadIdx.x;
    if (i >= n4) return;
    float4 v = ((const float4*)src)[i];
    short4v o;
    o[0] = f2bf(v.x); o[1] = f2bf(v.y); o[2] = f2bf(v.z); o[3] = f2bf(v.w);
    ((short4v*)dst)[i] = o;
}

// dst[m][k ^ ((m&7)<<3)] = bf16(src[k][m]) : transposed + XOR-swizzled so the
// edge kernel's linear LDS copy yields conflict-free ds_read_b128 A-fragments.
__global__ void prep_w_swz(const float* __restrict__ src, short* __restrict__ dst,
                           int K, int C) {
    int i = blockIdx.x * 256 + threadIdx.x;
    if (i >= K * C) return;
    int m = i / K, k = i - m * K;
    dst[m * K + (k ^ ((m & 7) << 3))] = f2bf(src[k * C + m]);
}

// plain transpose (node kernel path): dst[c][k] = bf16(src[k][c])
__global__ void prep_transpose(const float* __restrict__ src,
                               short* __restrict__ dst, int K, int C) {
    int i = blockIdx.x * 256 + threadIdx.x;
    if (i >= K * C) return;
    int c = i / K, k = i - c * K;
    dst[i] = f2bf(src[k * C + c]);
}

// ---------- edge kernel ----------
// 1024 threads = 16 waves; 32 edges/wave (2 groups of 16); 512 edges/block.
__global__ __launch_bounds__(1024, 4) void edge_kernel(
    const short* __restrict__ featbf,
    const int* __restrict__ rows,
    const int* __restrict__ cols,
    const short* __restrict__ W12,      // swizzled: W1 [128][256] | W2 [128][128]
    const float* __restrict__ bm1,
    const float* __restrict__ bm2,
    float* __restrict__ agg)
{
    __shared__ __align__(16) short wlds[49152];   // 96 KB: W1 (64 KB) | W2 (32 KB)
    __shared__ float biasb[256];                  // bm1 | bm2
    const int tid = threadIdx.x;
    const int w = tid >> 6, l = tid & 63;
    const int q = l >> 4, l15 = l & 15;

    // stage weights (linear copy; source is pre-swizzled)
    {
        const short8* gs = (const short8*)W12;
        short8* ls = (short8*)wlds;
#pragma unroll
        for (int i = 0; i < 6; ++i) ls[i * 1024 + tid] = gs[i * 1024 + tid];
        if (tid < 128) biasb[tid] = bm1[tid];
        else if (tid < 256) biasb[tid] = bm2[tid - 128];
    }
    __syncthreads();

    const int ebase = blockIdx.x * 512 + w * 32;
    int nodeA[2];
    const short* sp[2];
    const short* dp[2];
#pragma unroll
    for (int eg = 0; eg < 2; ++eg) {
        int e = ebase + eg * 16 + l15;
        int ns = rows[e], nd = cols[e];
        nodeA[eg] = ns;
        sp[eg] = featbf + (size_t)ns * 128;
        dp[eg] = featbf + (size_t)nd * 128;
    }

    // ---- GEMM1: hT[128][16] = Wm1T(A, LDS) x msg_inT(B, gathered), K=256 ----
    floatx4 acc1[8][2];
#pragma unroll
    for (int mt = 0; mt < 8; ++mt)
#pragma unroll
        for (int eg = 0; eg < 2; ++eg) acc1[mt][eg] = (floatx4)(0.f);

#pragma unroll
    for (int kk = 0; kk < 8; ++kk) {
        short8 bfr[2];
#pragma unroll
        for (int eg = 0; eg < 2; ++eg) {
            const short* p = (kk < 4) ? (sp[eg] + kk * 32 + q * 8)
                                      : (dp[eg] + (kk - 4) * 32 + q * 8);
            bfr[eg] = *(const short8*)p;
        }
#pragma unroll
        for (int mt = 0; mt < 8; ++mt) {
            const int m = mt * 16 + l15;
            const int idx = m * 256 + ((kk * 32 + q * 8) ^ ((m & 7) << 3));
            short8 afr = *(const short8*)(wlds + idx);
#pragma unroll
            for (int eg = 0; eg < 2; ++eg)
                acc1[mt][eg] = __builtin_amdgcn_mfma_f32_16x16x32_bf16(
                    afr, bfr[eg], acc1[mt][eg], 0, 0, 0);
        }
    }

    // W1 region (64 KB) dead from here; per-wave 4 KB buffers alias over it.
    __syncthreads();
    short (*hb)[16][128] = (short (*)[16][128])wlds;   // [16 waves][16 e][128]
    const int swzw = (l15 & 7) << 3;

#pragma unroll
    for (int eg = 0; eg < 2; ++eg) {
        // ---- bias + sigmoid + transpose h to LDS ----
        // lane holds hT[m][e=l15], m = mt*16 + q*4 + r  ->  hb[w][l15][m ^ swzw]
#pragma unroll
        for (int mt = 0; mt < 8; ++mt) {
            const int k0 = mt * 16 + q * 4;
            short4v hv;
            hv[0] = f2bf(sigmoidf_(acc1[mt][eg][0] + biasb[k0 + 0]));
            hv[1] = f2bf(sigmoidf_(acc1[mt][eg][1] + biasb[k0 + 1]));
            hv[2] = f2bf(sigmoidf_(acc1[mt][eg][2] + biasb[k0 + 2]));
            hv[3] = f2bf(sigmoidf_(acc1[mt][eg][3] + biasb[k0 + 3]));
            *(short4v*)&hb[w][l15][k0 ^ swzw] = hv;
        }

        // ---- GEMM2: msgT[128][16] = Wm2T(A, LDS) x hT(B, LDS), K=128 ----
        floatx4 acc2[8];
#pragma unroll
        for (int i = 0; i < 8; ++i) acc2[i] = (floatx4)(0.f);
#pragma unroll
        for (int kk2 = 0; kk2 < 4; ++kk2) {
            short8 bfrag = *(const short8*)&hb[w][l15][(kk2 * 32 + q * 8) ^ swzw];
#pragma unroll
            for (int mt = 0; mt < 8; ++mt) {
                const int m = mt * 16 + l15;
                const int idx = 32768 + m * 128 + ((kk2 * 32 + q * 8) ^ ((m & 7) << 3));
                short8 afr = *(const short8*)(wlds + idx);
                acc2[mt] = __builtin_amdgcn_mfma_f32_16x16x32_bf16(
                    afr, bfrag, acc2[mt], 0, 0, 0);
            }
        }

        // ---- bias + softsign, msgT -> LDS (same-wave reuse of hb[w]) ----
        // lane holds msgT[m][e=l15], m = mt*16+q*4+r -> hb[w][l15][m ^ swzw]
#pragma unroll
        for (int mt = 0; mt < 8; ++mt) {
            const int mbase = mt * 16 + q * 4;
            short4v mv;
            mv[0] = f2bf(softsignf_(acc2[mt][0] + biasb[128 + mbase + 0]));
            mv[1] = f2bf(softsignf_(acc2[mt][1] + biasb[128 + mbase + 1]));
            mv[2] = f2bf(softsignf_(acc2[mt][2] + biasb[128 + mbase + 2]));
            mv[3] = f2bf(softsignf_(acc2[mt][3] + biasb[128 + mbase + 3]));
            *(short4v*)&hb[w][l15][mbase ^ swzw] = mv;
        }

        // ---- scatter, R1 pattern: per instruction 4 nodes x 16 consecutive
        // cols (full 64B lines) ----
        int nd[4];
#pragma unroll
        for (int r = 0; r < 4; ++r) nd[r] = rows[ebase + eg * 16 + q * 4 + r];
#pragma unroll
        for (int ct = 0; ct < 8; ++ct) {
            const int col = ct * 16 + l15;
#pragma unroll
            for (int r = 0; r < 4; ++r) {
                const int e = q * 4 + r;
                const float m = bf2f(hb[w][e][col ^ ((e & 7) << 3)]);
                atomicAdd(&agg[(size_t)nd[r] * 128 + col], m);
            }
        }
    }
}

// ---------- node kernel (unchanged, R1-verified) ----------
__global__ __launch_bounds__(256) void node_kernel(
    const float* __restrict__ feat,
    const float* __restrict__ agg,
    const float* __restrict__ temb,
    const short* __restrict__ Wf1T,
    const float* __restrict__ bf1v,
    const short* __restrict__ Wf2T,
    const float* __restrict__ bf2v,
    float* __restrict__ out)
{
    __shared__ __align__(16) short gbuf[4][16][128];
    const int tid = threadIdx.x;
    const int w = tid >> 6, l = tid & 63;
    const int l15 = l & 15, q = l >> 4;
    const int nbase = blockIdx.x * 64 + w * 16;
    if (nbase >= NN) return;

    const int nA = nbase + l15;
    const float* p0 = feat + (size_t)nA * 128 + q * 8;
    const float* p1 = agg + (size_t)nA * 128 + q * 8;
    const float* p2 = temb + (size_t)nA * 128 + q * 8;

    floatx4 acc[8];
#pragma unroll
    for (int i = 0; i < 8; ++i) acc[i] = (floatx4)(0.f);

#pragma unroll
    for (int kk = 0; kk < 12; ++kk) {                   // K = 384 = 12 x 32
        const float* ap = (kk < 4) ? (p0 + kk * 32)
                        : (kk < 8) ? (p1 + (kk - 4) * 32)
                                   : (p2 + (kk - 8) * 32);
        const float4 a0 = *(const float4*)(ap);
        const float4 a1 = *(const float4*)(ap + 4);
        short8 af;
        af[0] = f2bf(sigmoidf_(a0.x)); af[1] = f2bf(sigmoidf_(a0.y));
        af[2] = f2bf(sigmoidf_(a0.z)); af[3] = f2bf(sigmoidf_(a0.w));
        af[4] = f2bf(sigmoidf_(a1.x)); af[5] = f2bf(sigmoidf_(a1.y));
        af[6] = f2bf(sigmoidf_(a1.z)); af[7] = f2bf(sigmoidf_(a1.w));
        const int krow = kk * 32 + q * 8;
#pragma unroll
        for (int ct = 0; ct < 8; ++ct) {
            const int col = ct * 16 + l15;
            short8 bf = *(const short8*)(Wf1T + col * 384 + krow);
            acc[ct] = __builtin_amdgcn_mfma_f32_16x16x32_bf16(af, bf, acc[ct], 0, 0, 0);
        }
    }

#pragma unroll
    for (int ct = 0; ct < 8; ++ct) {
        const int col = ct * 16 + l15;
        const float b = bf1v[col];
#pragma unroll
        for (int r = 0; r < 4; ++r) {
            gbuf[w][q * 4 + r][col] = f2bf(sigmoidf_(acc[ct][r] + b));
        }
    }

    floatx4 acc2[8];
#pragma unroll
    for (int i = 0; i < 8; ++i) acc2[i] = (floatx4)(0.f);
#pragma unroll
    for (int kk = 0; kk < 4; ++kk) {
        const int krow = kk * 32 + q * 8;
        short8 af = *(const short8*)(&gbuf[w][l15][krow]);
#pragma unroll
        for (int ct = 0; ct < 8; ++ct) {
            const int col = ct * 16 + l15;
            short8 bf = *(const short8*)(Wf2T + col * 128 + krow);
            acc2[ct] = __builtin_amdgcn_mfma_f32_16x16x32_bf16(af, bf, acc2[ct], 0, 0, 0);
        }
    }

#pragma unroll
    for (int ct = 0; ct < 8; ++ct) {
        const int col = ct * 16 + l15;
        const float b = bf2v[col];
#pragma unroll
        for (int r = 0; r < 4; ++r) {
            const int node = nbase + q * 4 + r;
            out[(size_t)node * 128 + col] = softsignf_(acc2[ct][r] + b);
        }
    }
}

extern "C" void kernel_launch(void* const* d_in, const int* in_sizes, int n_in,
                              void* d_out, int out_size, void* d_ws, size_t ws_size,
                              hipStream_t stream)
{
    const float* feat = (const float*)d_in[0];
    const int* rows = (const int*)d_in[1];
    const int* cols = (const int*)d_in[2];
    const float* temb = (const float*)d_in[3];
    const float* Wm1 = (const float*)d_in[4];
    const float* bm1 = (const float*)d_in[5];
    const float* Wm2 = (const float*)d_in[6];
    const float* bm2 = (const float*)d_in[7];
    const float* Wf1 = (const float*)d_in[8];
    const float* bf1 = (const float*)d_in[9];
    const float* Wf2 = (const float*)d_in[10];
    const float* bf2 = (const float*)d_in[11];
    float* out = (float*)d_out;

    // Workspace layout (16B-aligned):
    //   agg    f32  [10000][128]      5,120,000 B
    //   featbf bf16 [10000][128]      2,560,000 B
    //   W12    bf16 swz W1|W2            98,304 B
    //   Wf1T   bf16 [128][384]           98,304 B
    //   Wf2T   bf16 [128][128]           32,768 B
    char* ws = (char*)d_ws;
    float* agg   = (float*)ws;
    short* fbf   = (short*)(ws + 5120000);
    short* W12   = (short*)(ws + 5120000 + 2560000);
    short* Wf1T  = (short*)(ws + 5120000 + 2560000 + 98304);
    short* Wf2T  = (short*)(ws + 5120000 + 2560000 + 98304 + 98304);

    hipMemsetAsync(agg, 0, (size_t)NN * 128 * sizeof(float), stream);
    feat2bf<<<(NN * 128 / 4 + 255) / 256, 256, 0, stream>>>(feat, fbf, NN * 128 / 4);
    prep_w_swz<<<(256 * 128 + 255) / 256, 256, 0, stream>>>(Wm1, W12, 256, 128);
    prep_w_swz<<<(128 * 128 + 255) / 256, 256, 0, stream>>>(Wm2, W12 + 32768, 128, 128);
    prep_transpose<<<(384 * 128 + 255) / 256, 256, 0, stream>>>(Wf1, Wf1T, 384, 128);
    prep_transpose<<<(128 * 128 + 255) / 256, 256, 0, stream>>>(Wf2, Wf2T, 128, 128);

    edge_kernel<<<NE / 512, 1024, 0, stream>>>(fbf, rows, cols, W12, bm1, bm2, agg);
    node_kernel<<<(NN + 63) / 64, 256, 0, stream>>>(feat, agg, temb, Wf1T, bf1, Wf2T, bf2, out);
}

// Round 5
// 264.841 us; speedup vs baseline: 4.1943x; 1.3241x over previous
//
#include <hip/hip_runtime.h>
#include <hip/hip_bf16.h>

// Graph message-passing layer, bf16 MFMA implementation, v5.
// v4 + device counting-sort of edges by source node, so the scatter becomes
// mostly node-uniform per 16-edge wave-group: in-register 16-edge reduction
// (LDS reads + shfl_xor over q) -> ~1 atomic per (node,col) per group.
// N=10000 nodes, E=640000 edges, F=M=O=128.

#define NN 10000
#define NE 640000

typedef __attribute__((ext_vector_type(8))) short short8;
typedef __attribute__((ext_vector_type(4))) short short4v;
typedef __attribute__((ext_vector_type(4))) float floatx4;

__device__ __forceinline__ short f2bf(float f) {
    union { float f; unsigned u; } v; v.f = f;
    unsigned r = v.u + 0x7fffu + ((v.u >> 16) & 1u);   // RNE, NaN-free inputs
    return (short)(r >> 16);
}
__device__ __forceinline__ float bf2f(short s) {
    union { unsigned u; float f; } v; v.u = ((unsigned)(unsigned short)s) << 16;
    return v.f;
}

__device__ __forceinline__ float sigmoidf_(float x) {
    return __builtin_amdgcn_rcpf(1.f + __expf(-x));
}
__device__ __forceinline__ float softsignf_(float x) {
    return x * __builtin_amdgcn_rcpf(1.f + fabsf(x));
}

// ---------- prep kernels ----------

__global__ void feat2bf(const float* __restrict__ src, short* __restrict__ dst, int n4) {
    int i = blockIdx.x * 256 + threadIdx.x;
    if (i >= n4) return;
    float4 v = ((const float4*)src)[i];
    short4v o;
    o[0] = f2bf(v.x); o[1] = f2bf(v.y); o[2] = f2bf(v.z); o[3] = f2bf(v.w);
    ((short4v*)dst)[i] = o;
}

// dst[m][k ^ ((m&7)<<3)] = bf16(src[k][m])
__global__ void prep_w_swz(const float* __restrict__ src, short* __restrict__ dst,
                           int K, int C) {
    int i = blockIdx.x * 256 + threadIdx.x;
    if (i >= K * C) return;
    int m = i / K, k = i - m * K;
    dst[m * K + (k ^ ((m & 7) << 3))] = f2bf(src[k * C + m]);
}

// plain transpose (node kernel path): dst[c][k] = bf16(src[k][c])
__global__ void prep_transpose(const float* __restrict__ src,
                               short* __restrict__ dst, int K, int C) {
    int i = blockIdx.x * 256 + threadIdx.x;
    if (i >= K * C) return;
    int c = i / K, k = i - c * K;
    dst[i] = f2bf(src[k * C + c]);
}

// ---------- counting-sort kernels ----------

__global__ void hist_kernel(const int* __restrict__ rows, int* __restrict__ counts) {
    int e = blockIdx.x * 256 + threadIdx.x;
    if (e < NE) atomicAdd(&counts[rows[e]], 1);
}

// exclusive prefix sum over counts[NN], single 1024-thread block
__global__ __launch_bounds__(1024) void scan_kernel(const int* __restrict__ counts,
                                                    int* __restrict__ nodeoff) {
    __shared__ int buf[1024];
    const int tid = threadIdx.x;
    const int base = tid * 10;                 // 1024*10 >= NN
    int loc[10]; int s = 0;
#pragma unroll
    for (int i = 0; i < 10; ++i) {
        int idx = base + i;
        int c = (idx < NN) ? counts[idx] : 0;
        loc[i] = s; s += c;
    }
    buf[tid] = s;
    __syncthreads();
    for (int off = 1; off < 1024; off <<= 1) {   // Hillis-Steele inclusive
        int v = (tid >= off) ? buf[tid - off] : 0;
        __syncthreads();
        buf[tid] += v;
        __syncthreads();
    }
    int pref = (tid == 0) ? 0 : buf[tid - 1];
#pragma unroll
    for (int i = 0; i < 10; ++i) {
        int idx = base + i;
        if (idx < NN) nodeoff[idx] = pref + loc[i];
    }
}

__global__ void reorder_kernel(const int* __restrict__ rows, const int* __restrict__ cols,
                               const int* __restrict__ nodeoff, int* __restrict__ cursor,
                               int* __restrict__ srows, int* __restrict__ scols) {
    int e = blockIdx.x * 256 + threadIdx.x;
    if (e >= NE) return;
    int r = rows[e];
    int p = nodeoff[r] + atomicAdd(&cursor[r], 1);
    srows[p] = r;
    scols[p] = cols[e];
}

// ---------- edge kernel ----------
// 1024 threads = 16 waves; 32 edges/wave (2 groups of 16); 512 edges/block.
__global__ __launch_bounds__(1024, 4) void edge_kernel(
    const short* __restrict__ featbf,
    const int* __restrict__ rows,     // sorted by node when sort path enabled
    const int* __restrict__ cols,
    const short* __restrict__ W12,    // swizzled: W1 [128][256] | W2 [128][128]
    const float* __restrict__ bm1,
    const float* __restrict__ bm2,
    float* __restrict__ agg)
{
    __shared__ __align__(16) short wlds[49152];   // 96 KB: W1 (64 KB) | W2 (32 KB)
    __shared__ float biasb[256];                  // bm1 | bm2
    const int tid = threadIdx.x;
    const int w = tid >> 6, l = tid & 63;
    const int q = l >> 4, l15 = l & 15;

    {
        const short8* gs = (const short8*)W12;
        short8* ls = (short8*)wlds;
#pragma unroll
        for (int i = 0; i < 6; ++i) ls[i * 1024 + tid] = gs[i * 1024 + tid];
        if (tid < 128) biasb[tid] = bm1[tid];
        else if (tid < 256) biasb[tid] = bm2[tid - 128];
    }
    __syncthreads();

    const int ebase = blockIdx.x * 512 + w * 32;
    int nodeA[2];
    const short* sp[2];
    const short* dp[2];
#pragma unroll
    for (int eg = 0; eg < 2; ++eg) {
        int e = ebase + eg * 16 + l15;
        int ns = rows[e], nd = cols[e];
        nodeA[eg] = ns;
        sp[eg] = featbf + (size_t)ns * 128;
        dp[eg] = featbf + (size_t)nd * 128;
    }

    // ---- GEMM1: hT[128][16] = Wm1T(A, LDS) x msg_inT(B, gathered), K=256 ----
    floatx4 acc1[8][2];
#pragma unroll
    for (int mt = 0; mt < 8; ++mt)
#pragma unroll
        for (int eg = 0; eg < 2; ++eg) acc1[mt][eg] = (floatx4)(0.f);

#pragma unroll
    for (int kk = 0; kk < 8; ++kk) {
        short8 bfr[2];
#pragma unroll
        for (int eg = 0; eg < 2; ++eg) {
            const short* p = (kk < 4) ? (sp[eg] + kk * 32 + q * 8)
                                      : (dp[eg] + (kk - 4) * 32 + q * 8);
            bfr[eg] = *(const short8*)p;
        }
#pragma unroll
        for (int mt = 0; mt < 8; ++mt) {
            const int m = mt * 16 + l15;
            const int idx = m * 256 + ((kk * 32 + q * 8) ^ ((m & 7) << 3));
            short8 afr = *(const short8*)(wlds + idx);
#pragma unroll
            for (int eg = 0; eg < 2; ++eg)
                acc1[mt][eg] = __builtin_amdgcn_mfma_f32_16x16x32_bf16(
                    afr, bfr[eg], acc1[mt][eg], 0, 0, 0);
        }
    }

    // W1 region (64 KB) dead from here; per-wave 4 KB buffers alias over it.
    __syncthreads();
    short (*hb)[16][128] = (short (*)[16][128])wlds;   // [16 waves][16 e][128]
    const int swzw = (l15 & 7) << 3;

#pragma unroll
    for (int eg = 0; eg < 2; ++eg) {
        // ---- bias + sigmoid + transpose h to LDS ----
#pragma unroll
        for (int mt = 0; mt < 8; ++mt) {
            const int k0 = mt * 16 + q * 4;
            short4v hv;
            hv[0] = f2bf(sigmoidf_(acc1[mt][eg][0] + biasb[k0 + 0]));
            hv[1] = f2bf(sigmoidf_(acc1[mt][eg][1] + biasb[k0 + 1]));
            hv[2] = f2bf(sigmoidf_(acc1[mt][eg][2] + biasb[k0 + 2]));
            hv[3] = f2bf(sigmoidf_(acc1[mt][eg][3] + biasb[k0 + 3]));
            *(short4v*)&hb[w][l15][k0 ^ swzw] = hv;
        }

        // ---- GEMM2: msgT[128][16] = Wm2T(A, LDS) x hT(B, LDS), K=128 ----
        floatx4 acc2[8];
#pragma unroll
        for (int i = 0; i < 8; ++i) acc2[i] = (floatx4)(0.f);
#pragma unroll
        for (int kk2 = 0; kk2 < 4; ++kk2) {
            short8 bfrag = *(const short8*)&hb[w][l15][(kk2 * 32 + q * 8) ^ swzw];
#pragma unroll
            for (int mt = 0; mt < 8; ++mt) {
                const int m = mt * 16 + l15;
                const int idx = 32768 + m * 128 + ((kk2 * 32 + q * 8) ^ ((m & 7) << 3));
                short8 afr = *(const short8*)(wlds + idx);
                acc2[mt] = __builtin_amdgcn_mfma_f32_16x16x32_bf16(
                    afr, bfrag, acc2[mt], 0, 0, 0);
            }
        }

        // ---- bias + softsign, msgT -> LDS (same-wave reuse of hb[w]) ----
#pragma unroll
        for (int mt = 0; mt < 8; ++mt) {
            const int mbase = mt * 16 + q * 4;
            short4v mv;
            mv[0] = f2bf(softsignf_(acc2[mt][0] + biasb[128 + mbase + 0]));
            mv[1] = f2bf(softsignf_(acc2[mt][1] + biasb[128 + mbase + 1]));
            mv[2] = f2bf(softsignf_(acc2[mt][2] + biasb[128 + mbase + 2]));
            mv[3] = f2bf(softsignf_(acc2[mt][3] + biasb[128 + mbase + 3]));
            *(short4v*)&hb[w][l15][mbase ^ swzw] = mv;
        }

        // ---- aggregate + scatter ----
        // Sorted edges => 16-edge group usually all one node: reduce in-register
        // (4 LDS reads + butterfly over q) -> 1 atomic per col per group.
        const int n0 = __shfl(nodeA[eg], 0);
        const bool uni = (bool)__all(nodeA[eg] == n0);
        if (uni) {
#pragma unroll
            for (int ct = 0; ct < 8; ++ct) {
                const int col = ct * 16 + l15;
                float sum = 0.f;
#pragma unroll
                for (int r = 0; r < 4; ++r) {
                    const int e = q * 4 + r;
                    sum += bf2f(hb[w][e][col ^ ((e & 7) << 3)]);
                }
                sum += __shfl_xor(sum, 16);
                sum += __shfl_xor(sum, 32);
                if (q == 0) atomicAdd(&agg[(size_t)n0 * 128 + col], sum);
            }
        } else {
            // boundary group: per-lane run-detection over its 4 sorted edges
            int nd[4];
#pragma unroll
            for (int r = 0; r < 4; ++r) nd[r] = __shfl(nodeA[eg], q * 4 + r);
#pragma unroll
            for (int ct = 0; ct < 8; ++ct) {
                const int col = ct * 16 + l15;
                float run = 0.f;
#pragma unroll
                for (int r = 0; r < 4; ++r) {
                    const int e = q * 4 + r;
                    run += bf2f(hb[w][e][col ^ ((e & 7) << 3)]);
                    if (r == 3 || nd[r + 1] != nd[r]) {
                        atomicAdd(&agg[(size_t)nd[r] * 128 + col], run);
                        run = 0.f;
                    }
                }
            }
        }
    }
}

// ---------- node kernel (unchanged, R1-verified) ----------
__global__ __launch_bounds__(256) void node_kernel(
    const float* __restrict__ feat,
    const float* __restrict__ agg,
    const float* __restrict__ temb,
    const short* __restrict__ Wf1T,
    const float* __restrict__ bf1v,
    const short* __restrict__ Wf2T,
    const float* __restrict__ bf2v,
    float* __restrict__ out)
{
    __shared__ __align__(16) short gbuf[4][16][128];
    const int tid = threadIdx.x;
    const int w = tid >> 6, l = tid & 63;
    const int l15 = l & 15, q = l >> 4;
    const int nbase = blockIdx.x * 64 + w * 16;
    if (nbase >= NN) return;

    const int nA = nbase + l15;
    const float* p0 = feat + (size_t)nA * 128 + q * 8;
    const float* p1 = agg + (size_t)nA * 128 + q * 8;
    const float* p2 = temb + (size_t)nA * 128 + q * 8;

    floatx4 acc[8];
#pragma unroll
    for (int i = 0; i < 8; ++i) acc[i] = (floatx4)(0.f);

#pragma unroll
    for (int kk = 0; kk < 12; ++kk) {                   // K = 384 = 12 x 32
        const float* ap = (kk < 4) ? (p0 + kk * 32)
                        : (kk < 8) ? (p1 + (kk - 4) * 32)
                                   : (p2 + (kk - 8) * 32);
        const float4 a0 = *(const float4*)(ap);
        const float4 a1 = *(const float4*)(ap + 4);
        short8 af;
        af[0] = f2bf(sigmoidf_(a0.x)); af[1] = f2bf(sigmoidf_(a0.y));
        af[2] = f2bf(sigmoidf_(a0.z)); af[3] = f2bf(sigmoidf_(a0.w));
        af[4] = f2bf(sigmoidf_(a1.x)); af[5] = f2bf(sigmoidf_(a1.y));
        af[6] = f2bf(sigmoidf_(a1.z)); af[7] = f2bf(sigmoidf_(a1.w));
        const int krow = kk * 32 + q * 8;
#pragma unroll
        for (int ct = 0; ct < 8; ++ct) {
            const int col = ct * 16 + l15;
            short8 bf = *(const short8*)(Wf1T + col * 384 + krow);
            acc[ct] = __builtin_amdgcn_mfma_f32_16x16x32_bf16(af, bf, acc[ct], 0, 0, 0);
        }
    }

#pragma unroll
    for (int ct = 0; ct < 8; ++ct) {
        const int col = ct * 16 + l15;
        const float b = bf1v[col];
#pragma unroll
        for (int r = 0; r < 4; ++r) {
            gbuf[w][q * 4 + r][col] = f2bf(sigmoidf_(acc[ct][r] + b));
        }
    }

    floatx4 acc2[8];
#pragma unroll
    for (int i = 0; i < 8; ++i) acc2[i] = (floatx4)(0.f);
#pragma unroll
    for (int kk = 0; kk < 4; ++kk) {
        const int krow = kk * 32 + q * 8;
        short8 af = *(const short8*)(&gbuf[w][l15][krow]);
#pragma unroll
        for (int ct = 0; ct < 8; ++ct) {
            const int col = ct * 16 + l15;
            short8 bf = *(const short8*)(Wf2T + col * 128 + krow);
            acc2[ct] = __builtin_amdgcn_mfma_f32_16x16x32_bf16(af, bf, acc2[ct], 0, 0, 0);
        }
    }

#pragma unroll
    for (int ct = 0; ct < 8; ++ct) {
        const int col = ct * 16 + l15;
        const float b = bf2v[col];
#pragma unroll
        for (int r = 0; r < 4; ++r) {
            const int node = nbase + q * 4 + r;
            out[(size_t)node * 128 + col] = softsignf_(acc2[ct][r] + b);
        }
    }
}

extern "C" void kernel_launch(void* const* d_in, const int* in_sizes, int n_in,
                              void* d_out, int out_size, void* d_ws, size_t ws_size,
                              hipStream_t stream)
{
    const float* feat = (const float*)d_in[0];
    const int* rows = (const int*)d_in[1];
    const int* cols = (const int*)d_in[2];
    const float* temb = (const float*)d_in[3];
    const float* Wm1 = (const float*)d_in[4];
    const float* bm1 = (const float*)d_in[5];
    const float* Wm2 = (const float*)d_in[6];
    const float* bm2 = (const float*)d_in[7];
    const float* Wf1 = (const float*)d_in[8];
    const float* bf1 = (const float*)d_in[9];
    const float* Wf2 = (const float*)d_in[10];
    const float* bf2 = (const float*)d_in[11];
    float* out = (float*)d_out;

    // Workspace layout (16B-aligned):
    //   agg    f32  [10000][128]      5,120,000 B   @ 0
    //   featbf bf16 [10000][128]      2,560,000 B   @ 5,120,000
    //   W12    bf16 swz W1|W2            98,304 B   @ 7,680,000
    //   Wf1T   bf16 [128][384]           98,304 B   @ 7,778,304
    //   Wf2T   bf16 [128][128]           32,768 B   @ 7,876,608
    //   srows  i32  [NE]              2,560,000 B   @ 7,909,376
    //   scols  i32  [NE]              2,560,000 B   @ 10,469,376
    //   counts i32  [NN]                 40,000 B   @ 13,029,376
    //   nodeoff i32 [NN]                 40,000 B   @ 13,069,376
    //   cursor i32  [NN]                 40,000 B   @ 13,109,376
    char* ws = (char*)d_ws;
    float* agg   = (float*)ws;
    short* fbf   = (short*)(ws + 5120000);
    short* W12   = (short*)(ws + 7680000);
    short* Wf1T  = (short*)(ws + 7778304);
    short* Wf2T  = (short*)(ws + 7876608);
    int* srows   = (int*)(ws + 7909376);
    int* scols   = (int*)(ws + 10469376);
    int* counts  = (int*)(ws + 13029376);
    int* nodeoff = (int*)(ws + 13069376);
    int* cursor  = (int*)(ws + 13109376);
    const size_t NEEDED = 13149376;

    hipMemsetAsync(agg, 0, (size_t)NN * 128 * sizeof(float), stream);
    feat2bf<<<(NN * 128 / 4 + 255) / 256, 256, 0, stream>>>(feat, fbf, NN * 128 / 4);
    prep_w_swz<<<(256 * 128 + 255) / 256, 256, 0, stream>>>(Wm1, W12, 256, 128);
    prep_w_swz<<<(128 * 128 + 255) / 256, 256, 0, stream>>>(Wm2, W12 + 32768, 128, 128);
    prep_transpose<<<(384 * 128 + 255) / 256, 256, 0, stream>>>(Wf1, Wf1T, 384, 128);
    prep_transpose<<<(128 * 128 + 255) / 256, 256, 0, stream>>>(Wf2, Wf2T, 128, 128);

    const int* erows = rows;
    const int* ecols = cols;
    if (ws_size >= NEEDED) {
        hipMemsetAsync(counts, 0, NN * sizeof(int), stream);
        hipMemsetAsync(cursor, 0, NN * sizeof(int), stream);
        hist_kernel<<<(NE + 255) / 256, 256, 0, stream>>>(rows, counts);
        scan_kernel<<<1, 1024, 0, stream>>>(counts, nodeoff);
        reorder_kernel<<<(NE + 255) / 256, 256, 0, stream>>>(rows, cols, nodeoff,
                                                             cursor, srows, scols);
        erows = srows;
        ecols = scols;
    }

    edge_kernel<<<NE / 512, 1024, 0, stream>>>(fbf, erows, ecols, W12, bm1, bm2, agg);
    node_kernel<<<(NN + 63) / 64, 256, 0, stream>>>(feat, agg, temb, Wf1T, bf1, Wf2T, bf2, out);
}

// Round 6
// 247.806 us; speedup vs baseline: 4.4826x; 1.0687x over previous
//
#include <hip/hip_runtime.h>
#include <hip/hip_bf16.h>

// Graph message-passing layer, bf16 MFMA implementation, v6.
// vs v5: GEMM2 is non-swapped (operand order flipped) so acc2 = msg[e][m];
// the 16-edge group reduction is pure-register (3 adds + 2 shfl_xor) and the
// atomic scatter is 16-lane coalesced full-line writes. msgT LDS round-trip
// removed. Prep + hist fused into one kernel; sorted edges packed as int2.
// N=10000 nodes, E=640000 edges, F=M=O=128.

#define NN 10000
#define NE 640000

typedef __attribute__((ext_vector_type(8))) short short8;
typedef __attribute__((ext_vector_type(4))) short short4v;
typedef __attribute__((ext_vector_type(4))) float floatx4;

__device__ __forceinline__ short f2bf(float f) {
    union { float f; unsigned u; } v; v.f = f;
    unsigned r = v.u + 0x7fffu + ((v.u >> 16) & 1u);   // RNE, NaN-free inputs
    return (short)(r >> 16);
}

__device__ __forceinline__ float sigmoidf_(float x) {
    return __builtin_amdgcn_rcpf(1.f + __expf(-x));
}
__device__ __forceinline__ float softsignf_(float x) {
    return x * __builtin_amdgcn_rcpf(1.f + fabsf(x));
}

// ---------- fused prep kernel ----------
// grid partitions: [0,1250) feat->bf16 | [1250,1378) Wm1 swz | [1378,1442) Wm2 swz
// | [1442,1634) Wf1 T | [1634,1698) Wf2 T | [1698,4198) hist
__global__ __launch_bounds__(256) void prep_all(
    const float* __restrict__ feat, const int* __restrict__ rows,
    const float* __restrict__ Wm1, const float* __restrict__ Wm2,
    const float* __restrict__ Wf1, const float* __restrict__ Wf2,
    short* __restrict__ fbf, short* __restrict__ W12,
    short* __restrict__ Wf1T, short* __restrict__ Wf2T,
    int* __restrict__ counts)
{
    const int bid = blockIdx.x, tid = threadIdx.x;
    if (bid < 1250) {                       // features f32 -> bf16, 4/thread
        int i = bid * 256 + tid;            // n4 = 320000, exact
        float4 v = ((const float4*)feat)[i];
        short4v o;
        o[0] = f2bf(v.x); o[1] = f2bf(v.y); o[2] = f2bf(v.z); o[3] = f2bf(v.w);
        ((short4v*)fbf)[i] = o;
    } else if (bid < 1378) {                // Wm1 [256][128] -> swz [128][256]
        int i = (bid - 1250) * 256 + tid;   // 32768, exact
        int m = i >> 8, k = i & 255;
        W12[m * 256 + (k ^ ((m & 7) << 3))] = f2bf(Wm1[k * 128 + m]);
    } else if (bid < 1442) {                // Wm2 [128][128] -> swz
        int i = (bid - 1378) * 256 + tid;   // 16384, exact
        int m = i >> 7, k = i & 127;
        W12[32768 + m * 128 + (k ^ ((m & 7) << 3))] = f2bf(Wm2[k * 128 + m]);
    } else if (bid < 1634) {                // Wf1 [384][128] -> T [128][384]
        int i = (bid - 1442) * 256 + tid;   // 49152, exact
        int c = i / 384, k = i - c * 384;
        Wf1T[i] = f2bf(Wf1[k * 128 + c]);
    } else if (bid < 1698) {                // Wf2 [128][128] -> T
        int i = (bid - 1634) * 256 + tid;   // 16384, exact
        int c = i >> 7, k = i & 127;
        Wf2T[i] = f2bf(Wf2[k * 128 + c]);
    } else {                                // histogram of rows
        int e = (bid - 1698) * 256 + tid;   // 640000, exact
        atomicAdd(&counts[rows[e]], 1);
    }
}

// exclusive prefix sum over counts[NN], single 1024-thread block
__global__ __launch_bounds__(1024) void scan_kernel(const int* __restrict__ counts,
                                                    int* __restrict__ nodeoff) {
    __shared__ int buf[1024];
    const int tid = threadIdx.x;
    const int base = tid * 10;                 // 1024*10 >= NN
    int loc[10]; int s = 0;
#pragma unroll
    for (int i = 0; i < 10; ++i) {
        int idx = base + i;
        int c = (idx < NN) ? counts[idx] : 0;
        loc[i] = s; s += c;
    }
    buf[tid] = s;
    __syncthreads();
    for (int off = 1; off < 1024; off <<= 1) {   // Hillis-Steele inclusive
        int v = (tid >= off) ? buf[tid - off] : 0;
        __syncthreads();
        buf[tid] += v;
        __syncthreads();
    }
    int pref = (tid == 0) ? 0 : buf[tid - 1];
#pragma unroll
    for (int i = 0; i < 10; ++i) {
        int idx = base + i;
        if (idx < NN) nodeoff[idx] = pref + loc[i];
    }
}

__global__ void reorder_kernel(const int* __restrict__ rows, const int* __restrict__ cols,
                               const int* __restrict__ nodeoff, int* __restrict__ cursor,
                               int2* __restrict__ e2) {
    int e = blockIdx.x * 256 + threadIdx.x;
    if (e >= NE) return;
    int r = rows[e];
    int p = nodeoff[r] + atomicAdd(&cursor[r], 1);
    e2[p] = make_int2(r, cols[e]);
}

__global__ void pack_edges(const int* __restrict__ rows, const int* __restrict__ cols,
                           int2* __restrict__ e2) {
    int e = blockIdx.x * 256 + threadIdx.x;
    if (e < NE) e2[e] = make_int2(rows[e], cols[e]);
}

// ---------- edge kernel ----------
// 1024 threads = 16 waves; 32 edges/wave (2 groups of 16); 512 edges/block.
__global__ __launch_bounds__(1024, 4) void edge_kernel(
    const short* __restrict__ featbf,
    const int2* __restrict__ e2,      // sorted (row, col) pairs
    const short* __restrict__ W12,    // swizzled: W1 [128][256] | W2 [128][128]
    const float* __restrict__ bm1,
    const float* __restrict__ bm2,
    float* __restrict__ agg)
{
    __shared__ __align__(16) short wlds[49152];   // 96 KB: W1 (64 KB) | W2 (32 KB)
    __shared__ float biasb[256];                  // bm1 | bm2
    const int tid = threadIdx.x;
    const int w = tid >> 6, l = tid & 63;
    const int q = l >> 4, l15 = l & 15;

    {
        const short8* gs = (const short8*)W12;
        short8* ls = (short8*)wlds;
#pragma unroll
        for (int i = 0; i < 6; ++i) ls[i * 1024 + tid] = gs[i * 1024 + tid];
        if (tid < 128) biasb[tid] = bm1[tid];
        else if (tid < 256) biasb[tid] = bm2[tid - 128];
    }
    __syncthreads();

    const int ebase = blockIdx.x * 512 + w * 32;
    int nodeA[2];
    const short* sp[2];
    const short* dp[2];
#pragma unroll
    for (int eg = 0; eg < 2; ++eg) {
        int2 ec = e2[ebase + eg * 16 + l15];
        nodeA[eg] = ec.x;
        sp[eg] = featbf + (size_t)ec.x * 128;
        dp[eg] = featbf + (size_t)ec.y * 128;
    }

    // ---- GEMM1 (swapped): hT[128][16] = Wm1T(A, LDS) x msg_inT(B, gathered) ----
    floatx4 acc1[8][2];
#pragma unroll
    for (int mt = 0; mt < 8; ++mt)
#pragma unroll
        for (int eg = 0; eg < 2; ++eg) acc1[mt][eg] = (floatx4)(0.f);

#pragma unroll
    for (int kk = 0; kk < 8; ++kk) {
        short8 bfr[2];
#pragma unroll
        for (int eg = 0; eg < 2; ++eg) {
            const short* p = (kk < 4) ? (sp[eg] + kk * 32 + q * 8)
                                      : (dp[eg] + (kk - 4) * 32 + q * 8);
            bfr[eg] = *(const short8*)p;
        }
#pragma unroll
        for (int mt = 0; mt < 8; ++mt) {
            const int m = mt * 16 + l15;
            const int idx = m * 256 + ((kk * 32 + q * 8) ^ ((m & 7) << 3));
            short8 afr = *(const short8*)(wlds + idx);
#pragma unroll
            for (int eg = 0; eg < 2; ++eg)
                acc1[mt][eg] = __builtin_amdgcn_mfma_f32_16x16x32_bf16(
                    afr, bfr[eg], acc1[mt][eg], 0, 0, 0);
        }
    }

    // W1 region (64 KB) dead from here; per-wave 4 KB h-buffers alias over it.
    __syncthreads();
    short (*hb)[16][128] = (short (*)[16][128])wlds;   // [16 waves][16 e][128]
    const int swzw = (l15 & 7) << 3;

#pragma unroll
    for (int eg = 0; eg < 2; ++eg) {
        // ---- bias + sigmoid + transpose h to LDS ----
        // lane holds hT[m][e=l15], m = mt*16 + q*4 + r  ->  hb[w][l15][m ^ swzw]
#pragma unroll
        for (int mt = 0; mt < 8; ++mt) {
            const int k0 = mt * 16 + q * 4;
            short4v hv;
            hv[0] = f2bf(sigmoidf_(acc1[mt][eg][0] + biasb[k0 + 0]));
            hv[1] = f2bf(sigmoidf_(acc1[mt][eg][1] + biasb[k0 + 1]));
            hv[2] = f2bf(sigmoidf_(acc1[mt][eg][2] + biasb[k0 + 2]));
            hv[3] = f2bf(sigmoidf_(acc1[mt][eg][3] + biasb[k0 + 3]));
            *(short4v*)&hb[w][l15][k0 ^ swzw] = hv;
        }

        // ---- GEMM2 (non-swapped): msg[16 e][128 m] = h(A, LDS) x Wm2(B, LDS) ----
        // A-fragment: row=e=l15, k-slice q*8 -> same hb read as v5's bfrag.
        // B-fragment: col=m=mt*16+l15 -> same wlds read as v5's afr.
        floatx4 acc2[8];
#pragma unroll
        for (int i = 0; i < 8; ++i) acc2[i] = (floatx4)(0.f);
#pragma unroll
        for (int kk2 = 0; kk2 < 4; ++kk2) {
            short8 hfr = *(const short8*)&hb[w][l15][(kk2 * 32 + q * 8) ^ swzw];
#pragma unroll
            for (int mt = 0; mt < 8; ++mt) {
                const int m = mt * 16 + l15;
                const int idx = 32768 + m * 128 + ((kk2 * 32 + q * 8) ^ ((m & 7) << 3));
                short8 wfr = *(const short8*)(wlds + idx);
                acc2[mt] = __builtin_amdgcn_mfma_f32_16x16x32_bf16(
                    hfr, wfr, acc2[mt], 0, 0, 0);   // note operand order: h is A
            }
        }

        // ---- softsign + in-register 16-edge reduction + coalesced scatter ----
        // acc2[mt][r] = msg[e=q*4+r][m=mt*16+l15] (pre-bias)
        const int n0 = __shfl(nodeA[eg], 0);
        const bool uni = (bool)__all(nodeA[eg] == n0);
        if (uni) {
#pragma unroll
            for (int mt = 0; mt < 8; ++mt) {
                const float b = biasb[128 + mt * 16 + l15];
                float s = softsignf_(acc2[mt][0] + b) + softsignf_(acc2[mt][1] + b)
                        + softsignf_(acc2[mt][2] + b) + softsignf_(acc2[mt][3] + b);
                s += __shfl_xor(s, 16);
                s += __shfl_xor(s, 32);
                if (q == 0) atomicAdd(&agg[(size_t)n0 * 128 + mt * 16 + l15], s);
            }
        } else {
            // boundary group: per-lane run-detection over its 4 sorted edges
            int nd[4];
#pragma unroll
            for (int r = 0; r < 4; ++r) nd[r] = __shfl(nodeA[eg], q * 4 + r);
#pragma unroll
            for (int mt = 0; mt < 8; ++mt) {
                const float b = biasb[128 + mt * 16 + l15];
                float run = 0.f;
#pragma unroll
                for (int r = 0; r < 4; ++r) {
                    run += softsignf_(acc2[mt][r] + b);
                    if (r == 3 || nd[r + 1] != nd[r]) {
                        atomicAdd(&agg[(size_t)nd[r] * 128 + mt * 16 + l15], run);
                        run = 0.f;
                    }
                }
            }
        }
    }
}

// ---------- node kernel (unchanged, R1-verified) ----------
__global__ __launch_bounds__(256) void node_kernel(
    const float* __restrict__ feat,
    const float* __restrict__ agg,
    const float* __restrict__ temb,
    const short* __restrict__ Wf1T,
    const float* __restrict__ bf1v,
    const short* __restrict__ Wf2T,
    const float* __restrict__ bf2v,
    float* __restrict__ out)
{
    __shared__ __align__(16) short gbuf[4][16][128];
    const int tid = threadIdx.x;
    const int w = tid >> 6, l = tid & 63;
    const int l15 = l & 15, q = l >> 4;
    const int nbase = blockIdx.x * 64 + w * 16;
    if (nbase >= NN) return;

    const int nA = nbase + l15;
    const float* p0 = feat + (size_t)nA * 128 + q * 8;
    const float* p1 = agg + (size_t)nA * 128 + q * 8;
    const float* p2 = temb + (size_t)nA * 128 + q * 8;

    floatx4 acc[8];
#pragma unroll
    for (int i = 0; i < 8; ++i) acc[i] = (floatx4)(0.f);

#pragma unroll
    for (int kk = 0; kk < 12; ++kk) {                   // K = 384 = 12 x 32
        const float* ap = (kk < 4) ? (p0 + kk * 32)
                        : (kk < 8) ? (p1 + (kk - 4) * 32)
                                   : (p2 + (kk - 8) * 32);
        const float4 a0 = *(const float4*)(ap);
        const float4 a1 = *(const float4*)(ap + 4);
        short8 af;
        af[0] = f2bf(sigmoidf_(a0.x)); af[1] = f2bf(sigmoidf_(a0.y));
        af[2] = f2bf(sigmoidf_(a0.z)); af[3] = f2bf(sigmoidf_(a0.w));
        af[4] = f2bf(sigmoidf_(a1.x)); af[5] = f2bf(sigmoidf_(a1.y));
        af[6] = f2bf(sigmoidf_(a1.z)); af[7] = f2bf(sigmoidf_(a1.w));
        const int krow = kk * 32 + q * 8;
#pragma unroll
        for (int ct = 0; ct < 8; ++ct) {
            const int col = ct * 16 + l15;
            short8 bf = *(const short8*)(Wf1T + col * 384 + krow);
            acc[ct] = __builtin_amdgcn_mfma_f32_16x16x32_bf16(af, bf, acc[ct], 0, 0, 0);
        }
    }

#pragma unroll
    for (int ct = 0; ct < 8; ++ct) {
        const int col = ct * 16 + l15;
        const float b = bf1v[col];
#pragma unroll
        for (int r = 0; r < 4; ++r) {
            gbuf[w][q * 4 + r][col] = f2bf(sigmoidf_(acc[ct][r] + b));
        }
    }

    floatx4 acc2[8];
#pragma unroll
    for (int i = 0; i < 8; ++i) acc2[i] = (floatx4)(0.f);
#pragma unroll
    for (int kk = 0; kk < 4; ++kk) {
        const int krow = kk * 32 + q * 8;
        short8 af = *(const short8*)(&gbuf[w][l15][krow]);
#pragma unroll
        for (int ct = 0; ct < 8; ++ct) {
            const int col = ct * 16 + l15;
            short8 bf = *(const short8*)(Wf2T + col * 128 + krow);
            acc2[ct] = __builtin_amdgcn_mfma_f32_16x16x32_bf16(af, bf, acc2[ct], 0, 0, 0);
        }
    }

#pragma unroll
    for (int ct = 0; ct < 8; ++ct) {
        const int col = ct * 16 + l15;
        const float b = bf2v[col];
#pragma unroll
        for (int r = 0; r < 4; ++r) {
            const int node = nbase + q * 4 + r;
            out[(size_t)node * 128 + col] = softsignf_(acc2[ct][r] + b);
        }
    }
}

extern "C" void kernel_launch(void* const* d_in, const int* in_sizes, int n_in,
                              void* d_out, int out_size, void* d_ws, size_t ws_size,
                              hipStream_t stream)
{
    const float* feat = (const float*)d_in[0];
    const int* rows = (const int*)d_in[1];
    const int* cols = (const int*)d_in[2];
    const float* temb = (const float*)d_in[3];
    const float* Wm1 = (const float*)d_in[4];
    const float* bm1 = (const float*)d_in[5];
    const float* Wm2 = (const float*)d_in[6];
    const float* bm2 = (const float*)d_in[7];
    const float* Wf1 = (const float*)d_in[8];
    const float* bf1 = (const float*)d_in[9];
    const float* Wf2 = (const float*)d_in[10];
    const float* bf2 = (const float*)d_in[11];
    float* out = (float*)d_out;

    // Workspace layout (16B-aligned):
    //   agg    f32  [10000][128]      5,120,000 B   @ 0
    //   fbf    bf16 [10000][128]      2,560,000 B   @ 5,120,000
    //   W12    bf16 swz W1|W2            98,304 B   @ 7,680,000
    //   Wf1T   bf16 [128][384]           98,304 B   @ 7,778,304
    //   Wf2T   bf16 [128][128]           32,768 B   @ 7,876,608
    //   e2     int2 [NE]              5,120,000 B   @ 7,909,376
    //   counts i32  [NN]                 40,000 B   @ 13,029,376
    //   cursor i32  [NN]                 40,000 B   @ 13,069,376
    //   nodeoff i32 [NN]                 40,000 B   @ 13,109,376
    char* ws = (char*)d_ws;
    float* agg   = (float*)ws;
    short* fbf   = (short*)(ws + 5120000);
    short* W12   = (short*)(ws + 7680000);
    short* Wf1T  = (short*)(ws + 7778304);
    short* Wf2T  = (short*)(ws + 7876608);
    int2* e2     = (int2*)(ws + 7909376);
    int* counts  = (int*)(ws + 13029376);
    int* cursor  = (int*)(ws + 13069376);
    int* nodeoff = (int*)(ws + 13109376);
    const size_t NEEDED = 13149376;

    hipMemsetAsync(agg, 0, (size_t)NN * 128 * sizeof(float), stream);

    if (ws_size >= NEEDED) {
        hipMemsetAsync(counts, 0, 2 * NN * sizeof(int), stream);  // counts+cursor
        prep_all<<<4198, 256, 0, stream>>>(feat, rows, Wm1, Wm2, Wf1, Wf2,
                                           fbf, W12, Wf1T, Wf2T, counts);
        scan_kernel<<<1, 1024, 0, stream>>>(counts, nodeoff);
        reorder_kernel<<<(NE + 255) / 256, 256, 0, stream>>>(rows, cols, nodeoff,
                                                             cursor, e2);
    } else {
        prep_all<<<4198, 256, 0, stream>>>(feat, rows, Wm1, Wm2, Wf1, Wf2,
                                           fbf, W12, Wf1T, Wf2T, counts);
        pack_edges<<<(NE + 255) / 256, 256, 0, stream>>>(rows, cols, e2);
    }

    edge_kernel<<<NE / 512, 1024, 0, stream>>>(fbf, e2, W12, bm1, bm2, agg);
    node_kernel<<<(NN + 63) / 64, 256, 0, stream>>>(feat, agg, temb, Wf1T, bf1, Wf2T, bf2, out);
}